// Round 2
// baseline (1357.302 us; speedup 1.0000x reference)
//
#include <hip/hip_runtime.h>

// ---------------------------------------------------------------------------
// GCN encoder (VGAE): 3x GCNConv over N=100000 nodes, E=1.6M edges.
//   conv(X,W,b): H = X@W; agg[dst] += H[src]*dis[src]*dis[dst];
//                Y = act(agg + H*dis^2 + b)
// Layers: 128->64 (relu), 64->64 (relu), 64->[32 mu | 32 logvar] (none).
// mu/lv convs share edges+input -> fused via packed weight [Wmu|Wlv] (64x64).
// Round 2: identical to round 1 (which hit a GPU-acquisition timeout, never
// ran). Atomic-scatter edge aggregation (unsafeAtomicAdd ->
// global_atomic_add_f32), tiled fp32 GEMM, finalize in-place into AGG.
// ---------------------------------------------------------------------------

__global__ __launch_bounds__(256) void hist_kernel(const int* __restrict__ dst,
                                                   int* __restrict__ cnt, int E) {
  int stride = gridDim.x * blockDim.x;
  for (int e = blockIdx.x * blockDim.x + threadIdx.x; e < E; e += stride)
    atomicAdd(&cnt[dst[e]], 1);
}

__global__ __launch_bounds__(256) void dis_kernel(const int* __restrict__ cnt,
                                                  float* __restrict__ dis, int N) {
  int i = blockIdx.x * blockDim.x + threadIdx.x;
  if (i < N) dis[i] = rsqrtf((float)cnt[i] + 1.0f);
}

__global__ __launch_bounds__(256) void packw_kernel(const float* __restrict__ Wmu,
                                                    const float* __restrict__ Wlv,
                                                    float* __restrict__ Wc) {
  int i = blockIdx.x * blockDim.x + threadIdx.x;  // 64*64 = 4096
  if (i < 64 * 64) {
    int k = i >> 6, c = i & 63;
    Wc[i] = (c < 32) ? Wmu[k * 32 + c] : Wlv[k * 32 + (c - 32)];
  }
}

// H(N x 64) = X(N x Din) @ W(Din x 64), Din in {128, 64}.
// Block: 64 rows x 64 cols, 256 threads, 4x4 micro-tile per thread.
__global__ __launch_bounds__(256) void gemm64_kernel(const float* __restrict__ X,
                                                     const float* __restrict__ W,
                                                     float* __restrict__ H,
                                                     int N, int Din) {
  __shared__ float sA[32][68];  // sA[k][m], +4 pad keeps float4 alignment
  __shared__ float sB[32][68];  // sB[k][n]
  const int tid = threadIdx.x;
  const int tc = tid & 15;   // 16 col-groups of 4
  const int tr = tid >> 4;   // 16 row-groups of 4
  const int row0 = blockIdx.x * 64;

  float acc[4][4];
#pragma unroll
  for (int i = 0; i < 4; ++i)
#pragma unroll
    for (int j = 0; j < 4; ++j) acc[i][j] = 0.f;

  for (int k0 = 0; k0 < Din; k0 += 32) {
#pragma unroll
    for (int i = tid; i < 64 * 32; i += 256) {  // X tile, coalesced over k
      int r = i >> 5, kk = i & 31;
      int gr = row0 + r;
      sA[kk][r] = (gr < N) ? X[(size_t)gr * Din + k0 + kk] : 0.f;
    }
#pragma unroll
    for (int i = tid; i < 32 * 64; i += 256) {  // W tile, coalesced over c
      int kk = i >> 6, c = i & 63;
      sB[kk][c] = W[(size_t)(k0 + kk) * 64 + c];
    }
    __syncthreads();
#pragma unroll
    for (int kk = 0; kk < 32; ++kk) {
      float4 a = *(const float4*)&sA[kk][tr * 4];
      float4 b = *(const float4*)&sB[kk][tc * 4];
      acc[0][0] += a.x * b.x; acc[0][1] += a.x * b.y; acc[0][2] += a.x * b.z; acc[0][3] += a.x * b.w;
      acc[1][0] += a.y * b.x; acc[1][1] += a.y * b.y; acc[1][2] += a.y * b.z; acc[1][3] += a.y * b.w;
      acc[2][0] += a.z * b.x; acc[2][1] += a.z * b.y; acc[2][2] += a.z * b.z; acc[2][3] += a.z * b.w;
      acc[3][0] += a.w * b.x; acc[3][1] += a.w * b.y; acc[3][2] += a.w * b.z; acc[3][3] += a.w * b.w;
    }
    __syncthreads();
  }
#pragma unroll
  for (int i = 0; i < 4; ++i) {
    int gr = row0 + tr * 4 + i;
    if (gr < N) {
      float4 v = make_float4(acc[i][0], acc[i][1], acc[i][2], acc[i][3]);
      *(float4*)&H[(size_t)gr * 64 + tc * 4] = v;
    }
  }
}

// agg[dst][lane] += H[src][lane] * dis[src] * dis[dst] ; wave-per-edge.
__global__ __launch_bounds__(256) void edge_agg_kernel(const float* __restrict__ H,
                                                       const int* __restrict__ src,
                                                       const int* __restrict__ dst,
                                                       const float* __restrict__ dis,
                                                       float* __restrict__ agg, int E) {
  const int lane = threadIdx.x & 63;
  const int gw = (blockIdx.x * blockDim.x + threadIdx.x) >> 6;
  const int nw = (gridDim.x * blockDim.x) >> 6;
  for (int e = gw; e < E; e += nw) {
    int s = src[e];           // wave-uniform broadcast load (1 cacheline)
    int d = dst[e];
    float nrm = dis[s] * dis[d];
    float v = H[(size_t)s * 64 + lane] * nrm;
    unsafeAtomicAdd(&agg[(size_t)d * 64 + lane], v);  // global_atomic_add_f32
  }
}

// Y[i] = act(agg[i] + H[i]*dis[n]^2 + b[c]); safe to run in-place (Y == agg).
__global__ __launch_bounds__(256) void finalize_kernel(const float* __restrict__ agg,
                                                       const float* __restrict__ H,
                                                       const float* __restrict__ dis,
                                                       const float* __restrict__ b,
                                                       float* __restrict__ Y,
                                                       int N, int relu) {
  int i = blockIdx.x * blockDim.x + threadIdx.x;
  if (i < N * 64) {
    int n = i >> 6, c = i & 63;
    float dd = dis[n];
    float v = agg[i] + H[i] * dd * dd + b[c];
    if (relu) v = fmaxf(v, 0.f);
    Y[i] = v;
  }
}

// Final layer: cols 0..31 -> mu (+bmu), cols 32..63 -> logvar (+blv).
__global__ __launch_bounds__(256) void finalize_mulv_kernel(const float* __restrict__ agg,
                                                            const float* __restrict__ H,
                                                            const float* __restrict__ dis,
                                                            const float* __restrict__ bmu,
                                                            const float* __restrict__ blv,
                                                            float* __restrict__ out, int N) {
  int i = blockIdx.x * blockDim.x + threadIdx.x;
  if (i < N * 64) {
    int n = i >> 6, c = i & 63;
    float dd = dis[n];
    float v = agg[i] + H[i] * dd * dd;
    if (c < 32)
      out[(size_t)n * 32 + c] = v + bmu[c];
    else
      out[(size_t)N * 32 + (size_t)n * 32 + (c - 32)] = v + blv[c - 32];
  }
}

extern "C" void kernel_launch(void* const* d_in, const int* in_sizes, int n_in,
                              void* d_out, int out_size, void* d_ws, size_t ws_size,
                              hipStream_t stream) {
  const float* x   = (const float*)d_in[0];
  const int*   ei  = (const int*)d_in[1];
  const float* W1  = (const float*)d_in[2];
  const float* b1  = (const float*)d_in[3];
  const float* W2  = (const float*)d_in[4];
  const float* b2  = (const float*)d_in[5];
  const float* Wmu = (const float*)d_in[6];
  const float* bmu = (const float*)d_in[7];
  const float* Wlv = (const float*)d_in[8];
  const float* blv = (const float*)d_in[9];

  const int N = in_sizes[0] / 128;
  const int E = in_sizes[1] / 2;
  const int* src = ei;
  const int* dst = ei + E;

  const size_t N64 = (size_t)N * 64;
  float* HBUF = (float*)d_ws;          // N*64
  float* AGG  = HBUF + N64;            // N*64 (finalize writes in place)
  float* dis  = AGG + N64;             // N
  int*   cnt  = (int*)(dis + N);       // N
  float* Wc   = (float*)(cnt + N);     // 64*64
  float* out  = (float*)d_out;

  const int elemBlocks = (int)((N64 + 255) / 256);
  const int gemmBlocks = (N + 63) / 64;

  // degrees -> dis = (deg+1)^{-1/2}; packed [Wmu|Wlv]
  hipMemsetAsync(cnt, 0, (size_t)N * 4, stream);
  hist_kernel<<<2048, 256, 0, stream>>>(dst, cnt, E);
  dis_kernel<<<(N + 255) / 256, 256, 0, stream>>>(cnt, dis, N);
  packw_kernel<<<16, 256, 0, stream>>>(Wmu, Wlv, Wc);

  // ----- layer 1: 128 -> 64, relu -----
  gemm64_kernel<<<gemmBlocks, 256, 0, stream>>>(x, W1, HBUF, N, 128);
  hipMemsetAsync(AGG, 0, N64 * 4, stream);
  edge_agg_kernel<<<2048, 256, 0, stream>>>(HBUF, src, dst, dis, AGG, E);
  finalize_kernel<<<elemBlocks, 256, 0, stream>>>(AGG, HBUF, dis, b1, AGG, N, 1);

  // ----- layer 2: 64 -> 64, relu -----
  gemm64_kernel<<<gemmBlocks, 256, 0, stream>>>(AGG, W2, HBUF, N, 64);
  hipMemsetAsync(AGG, 0, N64 * 4, stream);
  edge_agg_kernel<<<2048, 256, 0, stream>>>(HBUF, src, dst, dis, AGG, E);
  finalize_kernel<<<elemBlocks, 256, 0, stream>>>(AGG, HBUF, dis, b2, AGG, N, 1);

  // ----- layer 3: 64 -> [32 mu | 32 logvar] -----
  gemm64_kernel<<<gemmBlocks, 256, 0, stream>>>(AGG, Wc, HBUF, N, 64);
  hipMemsetAsync(AGG, 0, N64 * 4, stream);
  edge_agg_kernel<<<2048, 256, 0, stream>>>(HBUF, src, dst, dis, AGG, E);
  finalize_mulv_kernel<<<elemBlocks, 256, 0, stream>>>(AGG, HBUF, dis, bmu, blv, out, N);
}

// Round 3
// 604.669 us; speedup vs baseline: 2.2447x; 2.2447x over previous
//
#include <hip/hip_runtime.h>

// ---------------------------------------------------------------------------
// GCN encoder (VGAE): 3x GCNConv over N=100000 nodes, E=1.6M edges.
// Round 3: CSR pull-aggregation. Round-2 counters showed edge_agg atomics
// wrote 409.6MB/pass through EA (WRITE_SIZE==E*64*4 exactly) at 1.9 TB/s
// combined -> 3x340us. Now: sort edges by dst once (hist + scan + scatter),
// then wave-per-dst-row register accumulation, finalize fused (no AGG
// memset, no separate finalize pass). mu/lv packed as before.
// ---------------------------------------------------------------------------

__global__ __launch_bounds__(256) void hist_kernel(const int* __restrict__ dst,
                                                   int* __restrict__ cnt, int E) {
  int stride = gridDim.x * blockDim.x;
  for (int e = blockIdx.x * blockDim.x + threadIdx.x; e < E; e += stride)
    atomicAdd(&cnt[dst[e]], 1);
}

__global__ __launch_bounds__(256) void dis_kernel(const int* __restrict__ cnt,
                                                  float* __restrict__ dis, int N) {
  int i = blockIdx.x * blockDim.x + threadIdx.x;
  if (i < N) dis[i] = rsqrtf((float)cnt[i] + 1.0f);
}

__global__ __launch_bounds__(256) void packw_kernel(const float* __restrict__ Wmu,
                                                    const float* __restrict__ Wlv,
                                                    float* __restrict__ Wc) {
  int i = blockIdx.x * blockDim.x + threadIdx.x;  // 64*64 = 4096
  if (i < 64 * 64) {
    int k = i >> 6, c = i & 63;
    Wc[i] = (c < 32) ? Wmu[k * 32 + c] : Wlv[k * 32 + (c - 32)];
  }
}

// ---- 3-phase exclusive scan of cnt[N] -> rowptr[N+1] ----
__global__ __launch_bounds__(256) void scanA_kernel(const int* __restrict__ cnt,
                                                    int* __restrict__ excl,
                                                    int* __restrict__ bsum, int N) {
  __shared__ int sm[256];
  const int tid = threadIdx.x;
  const int i = blockIdx.x * 256 + tid;
  int v = (i < N) ? cnt[i] : 0;
  sm[tid] = v;
  __syncthreads();
#pragma unroll
  for (int off = 1; off < 256; off <<= 1) {
    int t = (tid >= off) ? sm[tid - off] : 0;
    __syncthreads();
    sm[tid] += t;
    __syncthreads();
  }
  if (i < N) excl[i] = sm[tid] - v;          // exclusive within block
  if (tid == 255) bsum[blockIdx.x] = sm[255];  // block total
}

__global__ __launch_bounds__(512) void scanB_kernel(int* __restrict__ bsum, int nb) {
  __shared__ int sm[512];
  const int tid = threadIdx.x;
  int v = (tid < nb) ? bsum[tid] : 0;
  sm[tid] = v;
  __syncthreads();
#pragma unroll
  for (int off = 1; off < 512; off <<= 1) {
    int t = (tid >= off) ? sm[tid - off] : 0;
    __syncthreads();
    sm[tid] += t;
    __syncthreads();
  }
  if (tid < nb) bsum[tid] = sm[tid] - v;     // exclusive block offsets
}

__global__ __launch_bounds__(256) void scanC_kernel(int* __restrict__ rowptr,
                                                    const int* __restrict__ bsum,
                                                    int N, int E) {
  int i = blockIdx.x * 256 + threadIdx.x;
  if (i < N) rowptr[i] += bsum[i >> 8];
  if (i == 0) rowptr[N] = E;
}

// esrc[rowptr[d] + fill[d]++] = src[e]  (order within a row is arbitrary)
__global__ __launch_bounds__(256) void scatter_kernel(const int* __restrict__ src,
                                                      const int* __restrict__ dst,
                                                      const int* __restrict__ rowptr,
                                                      int* __restrict__ fill,
                                                      int* __restrict__ esrc, int E) {
  int stride = gridDim.x * blockDim.x;
  for (int e = blockIdx.x * blockDim.x + threadIdx.x; e < E; e += stride) {
    int d = dst[e];
    int pos = rowptr[d] + atomicAdd(&fill[d], 1);
    esrc[pos] = src[e];
  }
}

// H(N x 64) = X(N x Din) @ W(Din x 64), Din in {128, 64}.
__global__ __launch_bounds__(256) void gemm64_kernel(const float* __restrict__ X,
                                                     const float* __restrict__ W,
                                                     float* __restrict__ H,
                                                     int N, int Din) {
  __shared__ float sA[32][68];
  __shared__ float sB[32][68];
  const int tid = threadIdx.x;
  const int tc = tid & 15;
  const int tr = tid >> 4;
  const int row0 = blockIdx.x * 64;

  float acc[4][4];
#pragma unroll
  for (int i = 0; i < 4; ++i)
#pragma unroll
    for (int j = 0; j < 4; ++j) acc[i][j] = 0.f;

  for (int k0 = 0; k0 < Din; k0 += 32) {
#pragma unroll
    for (int i = tid; i < 64 * 32; i += 256) {
      int r = i >> 5, kk = i & 31;
      int gr = row0 + r;
      sA[kk][r] = (gr < N) ? X[(size_t)gr * Din + k0 + kk] : 0.f;
    }
#pragma unroll
    for (int i = tid; i < 32 * 64; i += 256) {
      int kk = i >> 6, c = i & 63;
      sB[kk][c] = W[(size_t)(k0 + kk) * 64 + c];
    }
    __syncthreads();
#pragma unroll
    for (int kk = 0; kk < 32; ++kk) {
      float4 a = *(const float4*)&sA[kk][tr * 4];
      float4 b = *(const float4*)&sB[kk][tc * 4];
      acc[0][0] += a.x * b.x; acc[0][1] += a.x * b.y; acc[0][2] += a.x * b.z; acc[0][3] += a.x * b.w;
      acc[1][0] += a.y * b.x; acc[1][1] += a.y * b.y; acc[1][2] += a.y * b.z; acc[1][3] += a.y * b.w;
      acc[2][0] += a.z * b.x; acc[2][1] += a.z * b.y; acc[2][2] += a.z * b.z; acc[2][3] += a.z * b.w;
      acc[3][0] += a.w * b.x; acc[3][1] += a.w * b.y; acc[3][2] += a.w * b.z; acc[3][3] += a.w * b.w;
    }
    __syncthreads();
  }
#pragma unroll
  for (int i = 0; i < 4; ++i) {
    int gr = row0 + tr * 4 + i;
    if (gr < N) {
      float4 v = make_float4(acc[i][0], acc[i][1], acc[i][2], acc[i][3]);
      *(float4*)&H[(size_t)gr * 64 + tc * 4] = v;
    }
  }
}

// Wave-per-row pull aggregation with fused finalize:
//   Y[n] = act( dis[n]*sum_{s in row n} H[s]*dis[s] + H[n]*dis[n]^2 + b )
__global__ __launch_bounds__(256) void agg_fused_kernel(const float* __restrict__ H,
                                                        const int* __restrict__ esrc,
                                                        const int* __restrict__ rowptr,
                                                        const float* __restrict__ dis,
                                                        const float* __restrict__ b,
                                                        float* __restrict__ Y,
                                                        int N, int relu) {
  const int lane = threadIdx.x & 63;
  const int row = (blockIdx.x * 256 + threadIdx.x) >> 6;
  if (row >= N) return;
  const int k1 = rowptr[row + 1];
  int k = rowptr[row];
  float acc = 0.f;
  for (; k + 4 <= k1; k += 4) {  // 4-way batch: group loads for MLP
    int s0 = esrc[k], s1 = esrc[k + 1], s2 = esrc[k + 2], s3 = esrc[k + 3];
    float w0 = dis[s0], w1 = dis[s1], w2 = dis[s2], w3 = dis[s3];
    float h0 = H[(size_t)s0 * 64 + lane], h1 = H[(size_t)s1 * 64 + lane];
    float h2 = H[(size_t)s2 * 64 + lane], h3 = H[(size_t)s3 * 64 + lane];
    acc += h0 * w0; acc += h1 * w1; acc += h2 * w2; acc += h3 * w3;
  }
  for (; k < k1; ++k) {
    int s = esrc[k];
    acc += H[(size_t)s * 64 + lane] * dis[s];
  }
  const float dd = dis[row];
  float v = acc * dd + H[(size_t)row * 64 + lane] * dd * dd + b[lane];
  if (relu) v = fmaxf(v, 0.f);
  Y[(size_t)row * 64 + lane] = v;
}

// Final layer variant: lanes 0..31 -> mu (+bmu), lanes 32..63 -> logvar (+blv).
__global__ __launch_bounds__(256) void agg_mulv_kernel(const float* __restrict__ H,
                                                       const int* __restrict__ esrc,
                                                       const int* __restrict__ rowptr,
                                                       const float* __restrict__ dis,
                                                       const float* __restrict__ bmu,
                                                       const float* __restrict__ blv,
                                                       float* __restrict__ out, int N) {
  const int lane = threadIdx.x & 63;
  const int row = (blockIdx.x * 256 + threadIdx.x) >> 6;
  if (row >= N) return;
  const int k1 = rowptr[row + 1];
  int k = rowptr[row];
  float acc = 0.f;
  for (; k + 4 <= k1; k += 4) {
    int s0 = esrc[k], s1 = esrc[k + 1], s2 = esrc[k + 2], s3 = esrc[k + 3];
    float w0 = dis[s0], w1 = dis[s1], w2 = dis[s2], w3 = dis[s3];
    float h0 = H[(size_t)s0 * 64 + lane], h1 = H[(size_t)s1 * 64 + lane];
    float h2 = H[(size_t)s2 * 64 + lane], h3 = H[(size_t)s3 * 64 + lane];
    acc += h0 * w0; acc += h1 * w1; acc += h2 * w2; acc += h3 * w3;
  }
  for (; k < k1; ++k) {
    int s = esrc[k];
    acc += H[(size_t)s * 64 + lane] * dis[s];
  }
  const float dd = dis[row];
  float v = acc * dd + H[(size_t)row * 64 + lane] * dd * dd;
  if (lane < 32)
    out[(size_t)row * 32 + lane] = v + bmu[lane];
  else
    out[(size_t)N * 32 + (size_t)row * 32 + (lane - 32)] = v + blv[lane - 32];
}

extern "C" void kernel_launch(void* const* d_in, const int* in_sizes, int n_in,
                              void* d_out, int out_size, void* d_ws, size_t ws_size,
                              hipStream_t stream) {
  const float* x   = (const float*)d_in[0];
  const int*   ei  = (const int*)d_in[1];
  const float* W1  = (const float*)d_in[2];
  const float* b1  = (const float*)d_in[3];
  const float* W2  = (const float*)d_in[4];
  const float* b2  = (const float*)d_in[5];
  const float* Wmu = (const float*)d_in[6];
  const float* bmu = (const float*)d_in[7];
  const float* Wlv = (const float*)d_in[8];
  const float* blv = (const float*)d_in[9];

  const int N = in_sizes[0] / 128;
  const int E = in_sizes[1] / 2;
  const int* src = ei;
  const int* dst = ei + E;

  const size_t N64 = (size_t)N * 64;
  float* HBUF   = (float*)d_ws;            // N*64
  float* YBUF   = HBUF + N64;              // N*64
  float* dis    = YBUF + N64;              // N
  int*   cnt    = (int*)(dis + N);         // N   (degree, then reused as fill)
  int*   rowptr = cnt + N;                 // N+1
  int*   bsum   = rowptr + N + 1;          // ceil(N/256) block sums
  int*   esrc   = bsum + 512;              // E   (dst-sorted src indices)
  float* Wc     = (float*)(esrc + E);      // 64*64
  float* out    = (float*)d_out;

  const int nb = (N + 255) / 256;          // scan blocks (391)
  const int rowBlocks = (N * 64 + 255) / 256;  // wave-per-row grids
  const int gemmBlocks = (N + 63) / 64;

  // ---- graph preprocessing: degrees, dis, CSR ----
  hipMemsetAsync(cnt, 0, (size_t)N * 4, stream);
  hist_kernel<<<2048, 256, 0, stream>>>(dst, cnt, E);
  dis_kernel<<<nb, 256, 0, stream>>>(cnt, dis, N);
  packw_kernel<<<16, 256, 0, stream>>>(Wmu, Wlv, Wc);
  scanA_kernel<<<nb, 256, 0, stream>>>(cnt, rowptr, bsum, N);
  scanB_kernel<<<1, 512, 0, stream>>>(bsum, nb);
  scanC_kernel<<<nb, 256, 0, stream>>>(rowptr, bsum, N, E);
  hipMemsetAsync(cnt, 0, (size_t)N * 4, stream);  // reuse as fill
  scatter_kernel<<<2048, 256, 0, stream>>>(src, dst, rowptr, cnt, esrc, E);

  // ---- layer 1: 128 -> 64, relu ----
  gemm64_kernel<<<gemmBlocks, 256, 0, stream>>>(x, W1, HBUF, N, 128);
  agg_fused_kernel<<<rowBlocks, 256, 0, stream>>>(HBUF, esrc, rowptr, dis, b1, YBUF, N, 1);

  // ---- layer 2: 64 -> 64, relu ----
  gemm64_kernel<<<gemmBlocks, 256, 0, stream>>>(YBUF, W2, HBUF, N, 64);
  agg_fused_kernel<<<rowBlocks, 256, 0, stream>>>(HBUF, esrc, rowptr, dis, b2, YBUF, N, 1);

  // ---- layer 3: 64 -> [32 mu | 32 logvar] ----
  gemm64_kernel<<<gemmBlocks, 256, 0, stream>>>(YBUF, Wc, HBUF, N, 64);
  agg_mulv_kernel<<<rowBlocks, 256, 0, stream>>>(HBUF, esrc, rowptr, dis, bmu, blv, out, N);
}

// Round 4
// 545.940 us; speedup vs baseline: 2.4862x; 1.1076x over previous
//
#include <hip/hip_runtime.h>
#include <hip/hip_fp16.h>

// ---------------------------------------------------------------------------
// GCN encoder (VGAE): 3x GCNConv, N=100000 nodes, E=1.6M edges.
// Round 4 changes (from r3 counters):
//  * scatter WRITE_SIZE was 107.6MB for 6.4MB payload (17x line-writeback
//    amplification, cross-XCD). Fix: bucket dst by (d&7), block q=bid%8
//    handles only bucket q -> each esrc line written by ONE XCD, accumulates
//    in its L2, writes back once. Edge stream re-read 8x but L3-served.
//  * agg gather was 1.6M x 256B fp32 rows. Fix: GEMM epilogue stores
//    Hs = H*dis as fp16 -> 128B/row gather, 12.8MB working set, and the
//    per-edge dis[s] load disappears: Y = dis[row]*(sum Hs[src] + Hs[row]) + b.
// ---------------------------------------------------------------------------

__global__ __launch_bounds__(256) void hist_kernel(const int* __restrict__ dst,
                                                   int* __restrict__ cnt, int E) {
  const int q  = blockIdx.x & 7;        // bucket == XCD (bid%8 round-robin)
  const int bi = blockIdx.x >> 3;
  const int stride = (gridDim.x >> 3) * blockDim.x;
  for (int e = bi * blockDim.x + threadIdx.x; e < E; e += stride) {
    int d = dst[e];
    if ((d & 7) == q) atomicAdd(&cnt[d], 1);
  }
}

__global__ __launch_bounds__(256) void dis_kernel(const int* __restrict__ cnt,
                                                  float* __restrict__ dis, int N) {
  int i = blockIdx.x * blockDim.x + threadIdx.x;
  if (i < N) dis[i] = rsqrtf((float)cnt[i] + 1.0f);
}

__global__ __launch_bounds__(256) void packw_kernel(const float* __restrict__ Wmu,
                                                    const float* __restrict__ Wlv,
                                                    float* __restrict__ Wc) {
  int i = blockIdx.x * blockDim.x + threadIdx.x;  // 64*64 = 4096
  if (i < 64 * 64) {
    int k = i >> 6, c = i & 63;
    Wc[i] = (c < 32) ? Wmu[k * 32 + c] : Wlv[k * 32 + (c - 32)];
  }
}

// ---- 3-phase exclusive scan of cnt[N] -> rowptr[N+1] ----
__global__ __launch_bounds__(256) void scanA_kernel(const int* __restrict__ cnt,
                                                    int* __restrict__ excl,
                                                    int* __restrict__ bsum, int N) {
  __shared__ int sm[256];
  const int tid = threadIdx.x;
  const int i = blockIdx.x * 256 + tid;
  int v = (i < N) ? cnt[i] : 0;
  sm[tid] = v;
  __syncthreads();
#pragma unroll
  for (int off = 1; off < 256; off <<= 1) {
    int t = (tid >= off) ? sm[tid - off] : 0;
    __syncthreads();
    sm[tid] += t;
    __syncthreads();
  }
  if (i < N) excl[i] = sm[tid] - v;
  if (tid == 255) bsum[blockIdx.x] = sm[255];
}

__global__ __launch_bounds__(512) void scanB_kernel(int* __restrict__ bsum, int nb) {
  __shared__ int sm[512];
  const int tid = threadIdx.x;
  int v = (tid < nb) ? bsum[tid] : 0;
  sm[tid] = v;
  __syncthreads();
#pragma unroll
  for (int off = 1; off < 512; off <<= 1) {
    int t = (tid >= off) ? sm[tid - off] : 0;
    __syncthreads();
    sm[tid] += t;
    __syncthreads();
  }
  if (tid < nb) bsum[tid] = sm[tid] - v;
}

__global__ __launch_bounds__(256) void scanC_kernel(int* __restrict__ rowptr,
                                                    const int* __restrict__ bsum,
                                                    int N, int E) {
  int i = blockIdx.x * 256 + threadIdx.x;
  if (i < N) rowptr[i] += bsum[i >> 8];
  if (i == 0) rowptr[N] = E;
}

// XCD-localized scatter: esrc[cursor[d]++] = src[e], bucket (d&7) on XCD bid%8.
__global__ __launch_bounds__(256) void scatter_kernel(const int* __restrict__ src,
                                                      const int* __restrict__ dst,
                                                      int* __restrict__ cursor,
                                                      int* __restrict__ esrc, int E) {
  const int q  = blockIdx.x & 7;
  const int bi = blockIdx.x >> 3;
  const int stride = (gridDim.x >> 3) * blockDim.x;
  for (int e = bi * blockDim.x + threadIdx.x; e < E; e += stride) {
    int d = dst[e];
    if ((d & 7) == q) {
      int pos = atomicAdd(&cursor[d], 1);
      esrc[pos] = src[e];
    }
  }
}

// Hs(N x 64) = (X(N x Din) @ W(Din x 64)) * dis[row], stored fp16.
__global__ __launch_bounds__(256) void gemm64_kernel(const float* __restrict__ X,
                                                     const float* __restrict__ W,
                                                     const float* __restrict__ dis,
                                                     __half* __restrict__ Hs,
                                                     int N, int Din) {
  __shared__ float sA[32][68];
  __shared__ float sB[32][68];
  const int tid = threadIdx.x;
  const int tc = tid & 15;
  const int tr = tid >> 4;
  const int row0 = blockIdx.x * 64;

  float acc[4][4];
#pragma unroll
  for (int i = 0; i < 4; ++i)
#pragma unroll
    for (int j = 0; j < 4; ++j) acc[i][j] = 0.f;

  for (int k0 = 0; k0 < Din; k0 += 32) {
#pragma unroll
    for (int i = tid; i < 64 * 32; i += 256) {
      int r = i >> 5, kk = i & 31;
      int gr = row0 + r;
      sA[kk][r] = (gr < N) ? X[(size_t)gr * Din + k0 + kk] : 0.f;
    }
#pragma unroll
    for (int i = tid; i < 32 * 64; i += 256) {
      int kk = i >> 6, c = i & 63;
      sB[kk][c] = W[(size_t)(k0 + kk) * 64 + c];
    }
    __syncthreads();
#pragma unroll
    for (int kk = 0; kk < 32; ++kk) {
      float4 a = *(const float4*)&sA[kk][tr * 4];
      float4 b = *(const float4*)&sB[kk][tc * 4];
      acc[0][0] += a.x * b.x; acc[0][1] += a.x * b.y; acc[0][2] += a.x * b.z; acc[0][3] += a.x * b.w;
      acc[1][0] += a.y * b.x; acc[1][1] += a.y * b.y; acc[1][2] += a.y * b.z; acc[1][3] += a.y * b.w;
      acc[2][0] += a.z * b.x; acc[2][1] += a.z * b.y; acc[2][2] += a.z * b.z; acc[2][3] += a.z * b.w;
      acc[3][0] += a.w * b.x; acc[3][1] += a.w * b.y; acc[3][2] += a.w * b.z; acc[3][3] += a.w * b.w;
    }
    __syncthreads();
  }
  unsigned short* hsu = (unsigned short*)Hs;
#pragma unroll
  for (int i = 0; i < 4; ++i) {
    int gr = row0 + tr * 4 + i;
    if (gr < N) {
      float dd = dis[gr];
      ushort4 v;
      v.x = __half_as_ushort(__float2half_rn(acc[i][0] * dd));
      v.y = __half_as_ushort(__float2half_rn(acc[i][1] * dd));
      v.z = __half_as_ushort(__float2half_rn(acc[i][2] * dd));
      v.w = __half_as_ushort(__float2half_rn(acc[i][3] * dd));
      *(ushort4*)&hsu[(size_t)gr * 64 + tc * 4] = v;  // 8B aligned store
    }
  }
}

// Wave-per-row pull aggregation, fused finalize:
//   Y[n] = act( dis[n] * ( sum_{s in row n} Hs[s] + Hs[n] ) + b )
__global__ __launch_bounds__(256) void agg_fused_kernel(const __half* __restrict__ Hs,
                                                        const int* __restrict__ esrc,
                                                        const int* __restrict__ rowptr,
                                                        const float* __restrict__ dis,
                                                        const float* __restrict__ b,
                                                        float* __restrict__ Y,
                                                        int N, int relu) {
  const int lane = threadIdx.x & 63;
  const int row = (blockIdx.x * 256 + threadIdx.x) >> 6;
  if (row >= N) return;
  const int k1 = rowptr[row + 1];
  int k = rowptr[row];
  float acc = 0.f;
  for (; k + 4 <= k1; k += 4) {
    int s0 = esrc[k], s1 = esrc[k + 1], s2 = esrc[k + 2], s3 = esrc[k + 3];
    float h0 = __half2float(Hs[(size_t)s0 * 64 + lane]);
    float h1 = __half2float(Hs[(size_t)s1 * 64 + lane]);
    float h2 = __half2float(Hs[(size_t)s2 * 64 + lane]);
    float h3 = __half2float(Hs[(size_t)s3 * 64 + lane]);
    acc += h0; acc += h1; acc += h2; acc += h3;
  }
  for (; k < k1; ++k)
    acc += __half2float(Hs[(size_t)esrc[k] * 64 + lane]);
  float v = dis[row] * (acc + __half2float(Hs[(size_t)row * 64 + lane])) + b[lane];
  if (relu) v = fmaxf(v, 0.f);
  Y[(size_t)row * 64 + lane] = v;
}

// Final layer: lanes 0..31 -> mu (+bmu), lanes 32..63 -> logvar (+blv).
__global__ __launch_bounds__(256) void agg_mulv_kernel(const __half* __restrict__ Hs,
                                                       const int* __restrict__ esrc,
                                                       const int* __restrict__ rowptr,
                                                       const float* __restrict__ dis,
                                                       const float* __restrict__ bmu,
                                                       const float* __restrict__ blv,
                                                       float* __restrict__ out, int N) {
  const int lane = threadIdx.x & 63;
  const int row = (blockIdx.x * 256 + threadIdx.x) >> 6;
  if (row >= N) return;
  const int k1 = rowptr[row + 1];
  int k = rowptr[row];
  float acc = 0.f;
  for (; k + 4 <= k1; k += 4) {
    int s0 = esrc[k], s1 = esrc[k + 1], s2 = esrc[k + 2], s3 = esrc[k + 3];
    float h0 = __half2float(Hs[(size_t)s0 * 64 + lane]);
    float h1 = __half2float(Hs[(size_t)s1 * 64 + lane]);
    float h2 = __half2float(Hs[(size_t)s2 * 64 + lane]);
    float h3 = __half2float(Hs[(size_t)s3 * 64 + lane]);
    acc += h0; acc += h1; acc += h2; acc += h3;
  }
  for (; k < k1; ++k)
    acc += __half2float(Hs[(size_t)esrc[k] * 64 + lane]);
  float v = dis[row] * (acc + __half2float(Hs[(size_t)row * 64 + lane]));
  if (lane < 32)
    out[(size_t)row * 32 + lane] = v + bmu[lane];
  else
    out[(size_t)N * 32 + (size_t)row * 32 + (lane - 32)] = v + blv[lane - 32];
}

extern "C" void kernel_launch(void* const* d_in, const int* in_sizes, int n_in,
                              void* d_out, int out_size, void* d_ws, size_t ws_size,
                              hipStream_t stream) {
  const float* x   = (const float*)d_in[0];
  const int*   ei  = (const int*)d_in[1];
  const float* W1  = (const float*)d_in[2];
  const float* b1  = (const float*)d_in[3];
  const float* W2  = (const float*)d_in[4];
  const float* b2  = (const float*)d_in[5];
  const float* Wmu = (const float*)d_in[6];
  const float* bmu = (const float*)d_in[7];
  const float* Wlv = (const float*)d_in[8];
  const float* blv = (const float*)d_in[9];

  const int N = in_sizes[0] / 128;
  const int E = in_sizes[1] / 2;
  const int* src = ei;
  const int* dst = ei + E;

  const size_t N64 = (size_t)N * 64;
  __half* Hs    = (__half*)d_ws;            // N*64 fp16 (12.8MB)
  float* YBUF   = (float*)(Hs + N64);       // N*64 fp32
  float* dis    = YBUF + N64;               // N
  int*   cnt    = (int*)(dis + N);          // N
  int*   rowptr = cnt + N;                  // N+1
  int*   bsum   = rowptr + N + 1;           // 512
  int*   cursor = bsum + 512;               // N
  int*   esrc   = cursor + N;               // E
  float* Wc     = (float*)(esrc + E);       // 64*64
  float* out    = (float*)d_out;

  const int nb = (N + 255) / 256;               // 391 scan blocks
  const int rowBlocks = (N * 64 + 255) / 256;   // wave-per-row grids
  const int gemmBlocks = (N + 63) / 64;

  // ---- graph preprocessing: degrees, dis, CSR (XCD-localized atomics) ----
  hipMemsetAsync(cnt, 0, (size_t)N * 4, stream);
  hist_kernel<<<2048, 256, 0, stream>>>(dst, cnt, E);
  dis_kernel<<<nb, 256, 0, stream>>>(cnt, dis, N);
  packw_kernel<<<16, 256, 0, stream>>>(Wmu, Wlv, Wc);
  scanA_kernel<<<nb, 256, 0, stream>>>(cnt, rowptr, bsum, N);
  scanB_kernel<<<1, 512, 0, stream>>>(bsum, nb);
  scanC_kernel<<<nb, 256, 0, stream>>>(rowptr, bsum, N, E);
  hipMemcpyAsync(cursor, rowptr, (size_t)N * 4, hipMemcpyDeviceToDevice, stream);
  scatter_kernel<<<2048, 256, 0, stream>>>(src, dst, cursor, esrc, E);

  // ---- layer 1: 128 -> 64, relu ----
  gemm64_kernel<<<gemmBlocks, 256, 0, stream>>>(x, W1, dis, Hs, N, 128);
  agg_fused_kernel<<<rowBlocks, 256, 0, stream>>>(Hs, esrc, rowptr, dis, b1, YBUF, N, 1);

  // ---- layer 2: 64 -> 64, relu ----
  gemm64_kernel<<<gemmBlocks, 256, 0, stream>>>(YBUF, W2, dis, Hs, N, 64);
  agg_fused_kernel<<<rowBlocks, 256, 0, stream>>>(Hs, esrc, rowptr, dis, b2, YBUF, N, 1);

  // ---- layer 3: 64 -> [32 mu | 32 logvar] ----
  gemm64_kernel<<<gemmBlocks, 256, 0, stream>>>(YBUF, Wc, dis, Hs, N, 64);
  agg_mulv_kernel<<<rowBlocks, 256, 0, stream>>>(Hs, esrc, rowptr, dis, bmu, blv, out, N);
}

// Round 5
// 449.721 us; speedup vs baseline: 3.0181x; 1.2140x over previous
//
#include <hip/hip_runtime.h>
#include <hip/hip_fp16.h>

// ---------------------------------------------------------------------------
// GCN encoder (VGAE): 3x GCNConv, N=100000 nodes, E=1.6M edges.
// Round 5: deterministic two-pass counting sort replaces the cursor-atomic
// scatter. R4 counters: scatter WRITE 83MB for 12.8MB payload -- esrc lines
// filled by writes spread over the whole kernel lifetime get evicted ~13x
// (dst/src streams flush the 4MB L2s). Fix = temporal compactness:
//   histk:  256 blocks x LDS hist over K=782 coarse buckets (dst>>7)
//   scan :  exclusive scan of hist2[K][256] (3-phase)
//   scat1:  each block writes packed (localRow<<17|src) into its private
//           contiguous segment of ebuf (sequential stores)
//   bsort:  one block per bucket: exact per-row CSR in LDS, dense esrc
//           writes (single writer per line), emits rowptr + dis directly.
// Deletes: old hist, dis, N-wide scan, cursor memcpy, cursor scatter.
// GEMM (epilogue Hs=H*dis fp16) and pull-agg unchanged from r4.
// ---------------------------------------------------------------------------

#define B1 256  // pass-1 block count (histk / scat1)

// per-block coarse histogram: hist2[k*B1 + b] = #edges of block b in bucket k
__global__ __launch_bounds__(256) void histk_kernel(const int* __restrict__ dst,
                                                    int* __restrict__ hist2,
                                                    int E, int K, int chunk) {
  __shared__ int h[1024];
  for (int i = threadIdx.x; i < K; i += 256) h[i] = 0;
  __syncthreads();
  const int e0 = blockIdx.x * chunk;
  const int e1 = min(E, e0 + chunk);
  for (int e = e0 + threadIdx.x; e < e1; e += 256)
    atomicAdd(&h[dst[e] >> 7], 1);
  __syncthreads();
  for (int i = threadIdx.x; i < K; i += 256)
    hist2[i * B1 + blockIdx.x] = h[i];
}

// ---- 3-phase exclusive scan over M = K*B1 ints (in-place safe) ----
__global__ __launch_bounds__(256) void scanA_kernel(const int* __restrict__ cnt,
                                                    int* __restrict__ excl,
                                                    int* __restrict__ bsum, int M) {
  __shared__ int sm[256];
  const int tid = threadIdx.x;
  const int i = blockIdx.x * 256 + tid;
  int v = (i < M) ? cnt[i] : 0;
  sm[tid] = v;
  __syncthreads();
#pragma unroll
  for (int off = 1; off < 256; off <<= 1) {
    int t = (tid >= off) ? sm[tid - off] : 0;
    __syncthreads();
    sm[tid] += t;
    __syncthreads();
  }
  if (i < M) excl[i] = sm[tid] - v;
  if (tid == 255) bsum[blockIdx.x] = sm[255];
}

__global__ __launch_bounds__(1024) void scanB_kernel(int* __restrict__ bsum, int nb) {
  __shared__ int sm[1024];
  const int tid = threadIdx.x;
  int v = (tid < nb) ? bsum[tid] : 0;
  sm[tid] = v;
  __syncthreads();
#pragma unroll
  for (int off = 1; off < 1024; off <<= 1) {
    int t = (tid >= off) ? sm[tid - off] : 0;
    __syncthreads();
    sm[tid] += t;
    __syncthreads();
  }
  if (tid < nb) bsum[tid] = sm[tid] - v;
}

__global__ __launch_bounds__(256) void scanC_kernel(int* __restrict__ data,
                                                    const int* __restrict__ bsum, int M) {
  int i = blockIdx.x * 256 + threadIdx.x;
  if (i < M) data[i] += bsum[i >> 8];
}

// pass-1 scatter: block b writes its edges into its private segment of each
// bucket: ebuf[off2[k][b] + local++] = (dstLocal<<17) | src  (sequential-ish)
__global__ __launch_bounds__(256) void scat1_kernel(const int* __restrict__ src,
                                                    const int* __restrict__ dst,
                                                    const int* __restrict__ off2,
                                                    int* __restrict__ ebuf,
                                                    int E, int K, int chunk) {
  __shared__ int base[1024];
  __shared__ int cur[1024];
  for (int i = threadIdx.x; i < K; i += 256) {
    base[i] = off2[i * B1 + blockIdx.x];
    cur[i] = 0;
  }
  __syncthreads();
  const int e0 = blockIdx.x * chunk;
  const int e1 = min(E, e0 + chunk);
  for (int e = e0 + threadIdx.x; e < e1; e += 256) {
    int d = dst[e];
    int k = d >> 7;
    int p = base[k] + atomicAdd(&cur[k], 1);
    ebuf[p] = ((d & 127) << 17) | src[e];  // src < 2^17 (N=100000)
  }
}

// pass-2: one block per bucket (128 rows). Exact per-row CSR in LDS; dense
// esrc writes; emits rowptr and dis. Reads its ebuf segment twice (L2-hot).
__global__ __launch_bounds__(256) void bsort_kernel(const int* __restrict__ ebuf,
                                                    const int* __restrict__ off2,
                                                    int* __restrict__ esrc,
                                                    int* __restrict__ rowptr,
                                                    float* __restrict__ dis,
                                                    int N, int E, int K) {
  const int k = blockIdx.x;
  const int tid = threadIdx.x;
  const int s0 = off2[k * B1];
  const int s1 = (k + 1 < K) ? off2[(k + 1) * B1] : E;
  const int cnt = s1 - s0;
  __shared__ int sm[128];
  __shared__ int rexcl[128];
  __shared__ int rcur[128];
  if (tid < 128) sm[tid] = 0;
  __syncthreads();
  for (int i = tid; i < cnt; i += 256)
    atomicAdd(&sm[ebuf[s0 + i] >> 17], 1);
  __syncthreads();
  int myc = (tid < 128) ? sm[tid] : 0;
#pragma unroll
  for (int off = 1; off < 128; off <<= 1) {  // Hillis-Steele inclusive
    int t = (tid >= off && tid < 128) ? sm[tid - off] : 0;
    __syncthreads();
    if (tid < 128) sm[tid] += t;
    __syncthreads();
  }
  if (tid < 128) {
    int ex = sm[tid] - myc;
    rexcl[tid] = ex;
    rcur[tid] = 0;
    int row = (k << 7) + tid;
    if (row < N) {
      rowptr[row] = s0 + ex;
      dis[row] = rsqrtf((float)myc + 1.0f);
    }
  }
  if (k == K - 1 && tid == 0) rowptr[N] = E;
  __syncthreads();
  for (int i = tid; i < cnt; i += 256) {
    int v = ebuf[s0 + i];
    int r = v >> 17;
    int p = s0 + rexcl[r] + atomicAdd(&rcur[r], 1);
    esrc[p] = v & 0x1FFFF;
  }
}

__global__ __launch_bounds__(256) void packw_kernel(const float* __restrict__ Wmu,
                                                    const float* __restrict__ Wlv,
                                                    float* __restrict__ Wc) {
  int i = blockIdx.x * blockDim.x + threadIdx.x;  // 64*64 = 4096
  if (i < 64 * 64) {
    int k = i >> 6, c = i & 63;
    Wc[i] = (c < 32) ? Wmu[k * 32 + c] : Wlv[k * 32 + (c - 32)];
  }
}

// Hs(N x 64) = (X(N x Din) @ W(Din x 64)) * dis[row], stored fp16.
__global__ __launch_bounds__(256) void gemm64_kernel(const float* __restrict__ X,
                                                     const float* __restrict__ W,
                                                     const float* __restrict__ dis,
                                                     __half* __restrict__ Hs,
                                                     int N, int Din) {
  __shared__ float sA[32][68];
  __shared__ float sB[32][68];
  const int tid = threadIdx.x;
  const int tc = tid & 15;
  const int tr = tid >> 4;
  const int row0 = blockIdx.x * 64;

  float acc[4][4];
#pragma unroll
  for (int i = 0; i < 4; ++i)
#pragma unroll
    for (int j = 0; j < 4; ++j) acc[i][j] = 0.f;

  for (int k0 = 0; k0 < Din; k0 += 32) {
#pragma unroll
    for (int i = tid; i < 64 * 32; i += 256) {
      int r = i >> 5, kk = i & 31;
      int gr = row0 + r;
      sA[kk][r] = (gr < N) ? X[(size_t)gr * Din + k0 + kk] : 0.f;
    }
#pragma unroll
    for (int i = tid; i < 32 * 64; i += 256) {
      int kk = i >> 6, c = i & 63;
      sB[kk][c] = W[(size_t)(k0 + kk) * 64 + c];
    }
    __syncthreads();
#pragma unroll
    for (int kk = 0; kk < 32; ++kk) {
      float4 a = *(const float4*)&sA[kk][tr * 4];
      float4 b = *(const float4*)&sB[kk][tc * 4];
      acc[0][0] += a.x * b.x; acc[0][1] += a.x * b.y; acc[0][2] += a.x * b.z; acc[0][3] += a.x * b.w;
      acc[1][0] += a.y * b.x; acc[1][1] += a.y * b.y; acc[1][2] += a.y * b.z; acc[1][3] += a.y * b.w;
      acc[2][0] += a.z * b.x; acc[2][1] += a.z * b.y; acc[2][2] += a.z * b.z; acc[2][3] += a.z * b.w;
      acc[3][0] += a.w * b.x; acc[3][1] += a.w * b.y; acc[3][2] += a.w * b.z; acc[3][3] += a.w * b.w;
    }
    __syncthreads();
  }
  unsigned short* hsu = (unsigned short*)Hs;
#pragma unroll
  for (int i = 0; i < 4; ++i) {
    int gr = row0 + tr * 4 + i;
    if (gr < N) {
      float dd = dis[gr];
      ushort4 v;
      v.x = __half_as_ushort(__float2half_rn(acc[i][0] * dd));
      v.y = __half_as_ushort(__float2half_rn(acc[i][1] * dd));
      v.z = __half_as_ushort(__float2half_rn(acc[i][2] * dd));
      v.w = __half_as_ushort(__float2half_rn(acc[i][3] * dd));
      *(ushort4*)&hsu[(size_t)gr * 64 + tc * 4] = v;
    }
  }
}

// Wave-per-row pull aggregation, fused finalize:
//   Y[n] = act( dis[n] * ( sum_{s in row n} Hs[s] + Hs[n] ) + b )
__global__ __launch_bounds__(256) void agg_fused_kernel(const __half* __restrict__ Hs,
                                                        const int* __restrict__ esrc,
                                                        const int* __restrict__ rowptr,
                                                        const float* __restrict__ dis,
                                                        const float* __restrict__ b,
                                                        float* __restrict__ Y,
                                                        int N, int relu) {
  const int lane = threadIdx.x & 63;
  const int row = (blockIdx.x * 256 + threadIdx.x) >> 6;
  if (row >= N) return;
  const int k1 = rowptr[row + 1];
  int k = rowptr[row];
  float acc = 0.f;
  for (; k + 4 <= k1; k += 4) {
    int s0 = esrc[k], s1 = esrc[k + 1], s2 = esrc[k + 2], s3 = esrc[k + 3];
    float h0 = __half2float(Hs[(size_t)s0 * 64 + lane]);
    float h1 = __half2float(Hs[(size_t)s1 * 64 + lane]);
    float h2 = __half2float(Hs[(size_t)s2 * 64 + lane]);
    float h3 = __half2float(Hs[(size_t)s3 * 64 + lane]);
    acc += h0; acc += h1; acc += h2; acc += h3;
  }
  for (; k < k1; ++k)
    acc += __half2float(Hs[(size_t)esrc[k] * 64 + lane]);
  float v = dis[row] * (acc + __half2float(Hs[(size_t)row * 64 + lane])) + b[lane];
  if (relu) v = fmaxf(v, 0.f);
  Y[(size_t)row * 64 + lane] = v;
}

// Final layer: lanes 0..31 -> mu (+bmu), lanes 32..63 -> logvar (+blv).
__global__ __launch_bounds__(256) void agg_mulv_kernel(const __half* __restrict__ Hs,
                                                       const int* __restrict__ esrc,
                                                       const int* __restrict__ rowptr,
                                                       const float* __restrict__ dis,
                                                       const float* __restrict__ bmu,
                                                       const float* __restrict__ blv,
                                                       float* __restrict__ out, int N) {
  const int lane = threadIdx.x & 63;
  const int row = (blockIdx.x * 256 + threadIdx.x) >> 6;
  if (row >= N) return;
  const int k1 = rowptr[row + 1];
  int k = rowptr[row];
  float acc = 0.f;
  for (; k + 4 <= k1; k += 4) {
    int s0 = esrc[k], s1 = esrc[k + 1], s2 = esrc[k + 2], s3 = esrc[k + 3];
    float h0 = __half2float(Hs[(size_t)s0 * 64 + lane]);
    float h1 = __half2float(Hs[(size_t)s1 * 64 + lane]);
    float h2 = __half2float(Hs[(size_t)s2 * 64 + lane]);
    float h3 = __half2float(Hs[(size_t)s3 * 64 + lane]);
    acc += h0; acc += h1; acc += h2; acc += h3;
  }
  for (; k < k1; ++k)
    acc += __half2float(Hs[(size_t)esrc[k] * 64 + lane]);
  float v = dis[row] * (acc + __half2float(Hs[(size_t)row * 64 + lane]));
  if (lane < 32)
    out[(size_t)row * 32 + lane] = v + bmu[lane];
  else
    out[(size_t)N * 32 + (size_t)row * 32 + (lane - 32)] = v + blv[lane - 32];
}

extern "C" void kernel_launch(void* const* d_in, const int* in_sizes, int n_in,
                              void* d_out, int out_size, void* d_ws, size_t ws_size,
                              hipStream_t stream) {
  const float* x   = (const float*)d_in[0];
  const int*   ei  = (const int*)d_in[1];
  const float* W1  = (const float*)d_in[2];
  const float* b1  = (const float*)d_in[3];
  const float* W2  = (const float*)d_in[4];
  const float* b2  = (const float*)d_in[5];
  const float* Wmu = (const float*)d_in[6];
  const float* bmu = (const float*)d_in[7];
  const float* Wlv = (const float*)d_in[8];
  const float* blv = (const float*)d_in[9];

  const int N = in_sizes[0] / 128;
  const int E = in_sizes[1] / 2;
  const int* src = ei;
  const int* dst = ei + E;

  const int K = (N + 127) >> 7;        // coarse buckets (782), K <= 1024
  const int M = K * B1;                // hist2 entries
  const int chunk = (E + B1 - 1) / B1; // edges per pass-1 block

  const size_t N64 = (size_t)N * 64;
  __half* Hs    = (__half*)d_ws;            // N*64 fp16
  float* YBUF   = (float*)(Hs + N64);       // N*64 fp32
  float* dis    = YBUF + N64;               // N
  int*   rowptr = (int*)(dis + N);          // N+1
  int*   hist2  = rowptr + N + 1;           // K*B1 (becomes off2 after scan)
  int*   bsum   = hist2 + M;                // K (<=1024)
  int*   ebuf   = bsum + 1024;              // E packed (local<<17|src)
  int*   esrc   = ebuf + E;                 // E (CSR column indices)
  float* Wc     = (float*)(esrc + E);       // 64*64
  float* out    = (float*)d_out;

  const int rowBlocks = (N * 64 + 255) / 256;
  const int gemmBlocks = (N + 63) / 64;

  // ---- CSR build: counting sort by dst (also yields rowptr and dis) ----
  histk_kernel<<<B1, 256, 0, stream>>>(dst, hist2, E, K, chunk);
  scanA_kernel<<<K, 256, 0, stream>>>(hist2, hist2, bsum, M);
  scanB_kernel<<<1, 1024, 0, stream>>>(bsum, K);
  scanC_kernel<<<K, 256, 0, stream>>>(hist2, bsum, M);
  scat1_kernel<<<B1, 256, 0, stream>>>(src, dst, hist2, ebuf, E, K, chunk);
  bsort_kernel<<<K, 256, 0, stream>>>(ebuf, hist2, esrc, rowptr, dis, N, E, K);
  packw_kernel<<<16, 256, 0, stream>>>(Wmu, Wlv, Wc);

  // ---- layer 1: 128 -> 64, relu ----
  gemm64_kernel<<<gemmBlocks, 256, 0, stream>>>(x, W1, dis, Hs, N, 128);
  agg_fused_kernel<<<rowBlocks, 256, 0, stream>>>(Hs, esrc, rowptr, dis, b1, YBUF, N, 1);

  // ---- layer 2: 64 -> 64, relu ----
  gemm64_kernel<<<gemmBlocks, 256, 0, stream>>>(YBUF, W2, dis, Hs, N, 64);
  agg_fused_kernel<<<rowBlocks, 256, 0, stream>>>(Hs, esrc, rowptr, dis, b2, YBUF, N, 1);

  // ---- layer 3: 64 -> [32 mu | 32 logvar] ----
  gemm64_kernel<<<gemmBlocks, 256, 0, stream>>>(YBUF, Wc, dis, Hs, N, 64);
  agg_mulv_kernel<<<rowBlocks, 256, 0, stream>>>(Hs, esrc, rowptr, dis, bmu, blv, out, N);
}

// Round 6
// 426.116 us; speedup vs baseline: 3.1853x; 1.0554x over previous
//
#include <hip/hip_runtime.h>
#include <hip/hip_fp16.h>

// ---------------------------------------------------------------------------
// GCN encoder (VGAE): 3x GCNConv, N=100000 nodes, E=1.6M edges.
// Round 6: agg restructure. R5 counters: agg FETCH 87.7MB ~= 8 XCD x 12.8MB
// Hs working set (L2-miss volume at structural floor), 1.73 TB/s << any BW
// ceiling, VALUBusy 36% -> latency/MLP-bound. Fix: half2 lanes (32 lanes
// cover 64 cols), two edges per wave (one per 32-lane half), 8 edges per
// main-loop iteration (4 independent line loads per half in flight),
// __shfl_xor(32) combine + float2 epilogue on half 0.
// CSR counting sort (histk/scan/scat1/bsort), fp16 Hs=H*dis GEMM epilogue,
// packed [Wmu|Wlv] unchanged from r5.
// ---------------------------------------------------------------------------

#define B1 256  // pass-1 block count (histk / scat1)

// per-block coarse histogram: hist2[k*B1 + b] = #edges of block b in bucket k
__global__ __launch_bounds__(256) void histk_kernel(const int* __restrict__ dst,
                                                    int* __restrict__ hist2,
                                                    int E, int K, int chunk) {
  __shared__ int h[1024];
  for (int i = threadIdx.x; i < K; i += 256) h[i] = 0;
  __syncthreads();
  const int e0 = blockIdx.x * chunk;
  const int e1 = min(E, e0 + chunk);
  for (int e = e0 + threadIdx.x; e < e1; e += 256)
    atomicAdd(&h[dst[e] >> 7], 1);
  __syncthreads();
  for (int i = threadIdx.x; i < K; i += 256)
    hist2[i * B1 + blockIdx.x] = h[i];
}

// ---- 3-phase exclusive scan over M = K*B1 ints (in-place safe) ----
__global__ __launch_bounds__(256) void scanA_kernel(const int* __restrict__ cnt,
                                                    int* __restrict__ excl,
                                                    int* __restrict__ bsum, int M) {
  __shared__ int sm[256];
  const int tid = threadIdx.x;
  const int i = blockIdx.x * 256 + tid;
  int v = (i < M) ? cnt[i] : 0;
  sm[tid] = v;
  __syncthreads();
#pragma unroll
  for (int off = 1; off < 256; off <<= 1) {
    int t = (tid >= off) ? sm[tid - off] : 0;
    __syncthreads();
    sm[tid] += t;
    __syncthreads();
  }
  if (i < M) excl[i] = sm[tid] - v;
  if (tid == 255) bsum[blockIdx.x] = sm[255];
}

__global__ __launch_bounds__(1024) void scanB_kernel(int* __restrict__ bsum, int nb) {
  __shared__ int sm[1024];
  const int tid = threadIdx.x;
  int v = (tid < nb) ? bsum[tid] : 0;
  sm[tid] = v;
  __syncthreads();
#pragma unroll
  for (int off = 1; off < 1024; off <<= 1) {
    int t = (tid >= off) ? sm[tid - off] : 0;
    __syncthreads();
    sm[tid] += t;
    __syncthreads();
  }
  if (tid < nb) bsum[tid] = sm[tid] - v;
}

__global__ __launch_bounds__(256) void scanC_kernel(int* __restrict__ data,
                                                    const int* __restrict__ bsum, int M) {
  int i = blockIdx.x * 256 + threadIdx.x;
  if (i < M) data[i] += bsum[i >> 8];
}

// pass-1 scatter: block b writes its edges into its private segment of each
// bucket: ebuf[off2[k][b] + local++] = (dstLocal<<17) | src
__global__ __launch_bounds__(256) void scat1_kernel(const int* __restrict__ src,
                                                    const int* __restrict__ dst,
                                                    const int* __restrict__ off2,
                                                    int* __restrict__ ebuf,
                                                    int E, int K, int chunk) {
  __shared__ int base[1024];
  __shared__ int cur[1024];
  for (int i = threadIdx.x; i < K; i += 256) {
    base[i] = off2[i * B1 + blockIdx.x];
    cur[i] = 0;
  }
  __syncthreads();
  const int e0 = blockIdx.x * chunk;
  const int e1 = min(E, e0 + chunk);
  for (int e = e0 + threadIdx.x; e < e1; e += 256) {
    int d = dst[e];
    int k = d >> 7;
    int p = base[k] + atomicAdd(&cur[k], 1);
    ebuf[p] = ((d & 127) << 17) | src[e];  // src < 2^17 (N=100000)
  }
}

// pass-2: one block per bucket (128 rows). Exact per-row CSR in LDS; dense
// esrc writes; emits rowptr and dis.
__global__ __launch_bounds__(256) void bsort_kernel(const int* __restrict__ ebuf,
                                                    const int* __restrict__ off2,
                                                    int* __restrict__ esrc,
                                                    int* __restrict__ rowptr,
                                                    float* __restrict__ dis,
                                                    int N, int E, int K) {
  const int k = blockIdx.x;
  const int tid = threadIdx.x;
  const int s0 = off2[k * B1];
  const int s1 = (k + 1 < K) ? off2[(k + 1) * B1] : E;
  const int cnt = s1 - s0;
  __shared__ int sm[128];
  __shared__ int rexcl[128];
  __shared__ int rcur[128];
  if (tid < 128) sm[tid] = 0;
  __syncthreads();
  for (int i = tid; i < cnt; i += 256)
    atomicAdd(&sm[ebuf[s0 + i] >> 17], 1);
  __syncthreads();
  int myc = (tid < 128) ? sm[tid] : 0;
#pragma unroll
  for (int off = 1; off < 128; off <<= 1) {  // Hillis-Steele inclusive
    int t = (tid >= off && tid < 128) ? sm[tid - off] : 0;
    __syncthreads();
    if (tid < 128) sm[tid] += t;
    __syncthreads();
  }
  if (tid < 128) {
    int ex = sm[tid] - myc;
    rexcl[tid] = ex;
    rcur[tid] = 0;
    int row = (k << 7) + tid;
    if (row < N) {
      rowptr[row] = s0 + ex;
      dis[row] = rsqrtf((float)myc + 1.0f);
    }
  }
  if (k == K - 1 && tid == 0) rowptr[N] = E;
  __syncthreads();
  for (int i = tid; i < cnt; i += 256) {
    int v = ebuf[s0 + i];
    int r = v >> 17;
    int p = s0 + rexcl[r] + atomicAdd(&rcur[r], 1);
    esrc[p] = v & 0x1FFFF;
  }
}

__global__ __launch_bounds__(256) void packw_kernel(const float* __restrict__ Wmu,
                                                    const float* __restrict__ Wlv,
                                                    float* __restrict__ Wc) {
  int i = blockIdx.x * blockDim.x + threadIdx.x;  // 64*64 = 4096
  if (i < 64 * 64) {
    int k = i >> 6, c = i & 63;
    Wc[i] = (c < 32) ? Wmu[k * 32 + c] : Wlv[k * 32 + (c - 32)];
  }
}

// Hs(N x 64) = (X(N x Din) @ W(Din x 64)) * dis[row], stored fp16.
__global__ __launch_bounds__(256) void gemm64_kernel(const float* __restrict__ X,
                                                     const float* __restrict__ W,
                                                     const float* __restrict__ dis,
                                                     __half* __restrict__ Hs,
                                                     int N, int Din) {
  __shared__ float sA[32][68];
  __shared__ float sB[32][68];
  const int tid = threadIdx.x;
  const int tc = tid & 15;
  const int tr = tid >> 4;
  const int row0 = blockIdx.x * 64;

  float acc[4][4];
#pragma unroll
  for (int i = 0; i < 4; ++i)
#pragma unroll
    for (int j = 0; j < 4; ++j) acc[i][j] = 0.f;

  for (int k0 = 0; k0 < Din; k0 += 32) {
#pragma unroll
    for (int i = tid; i < 64 * 32; i += 256) {
      int r = i >> 5, kk = i & 31;
      int gr = row0 + r;
      sA[kk][r] = (gr < N) ? X[(size_t)gr * Din + k0 + kk] : 0.f;
    }
#pragma unroll
    for (int i = tid; i < 32 * 64; i += 256) {
      int kk = i >> 6, c = i & 63;
      sB[kk][c] = W[(size_t)(k0 + kk) * 64 + c];
    }
    __syncthreads();
#pragma unroll
    for (int kk = 0; kk < 32; ++kk) {
      float4 a = *(const float4*)&sA[kk][tr * 4];
      float4 b = *(const float4*)&sB[kk][tc * 4];
      acc[0][0] += a.x * b.x; acc[0][1] += a.x * b.y; acc[0][2] += a.x * b.z; acc[0][3] += a.x * b.w;
      acc[1][0] += a.y * b.x; acc[1][1] += a.y * b.y; acc[1][2] += a.y * b.z; acc[1][3] += a.y * b.w;
      acc[2][0] += a.z * b.x; acc[2][1] += a.z * b.y; acc[2][2] += a.z * b.z; acc[2][3] += a.z * b.w;
      acc[3][0] += a.w * b.x; acc[3][1] += a.w * b.y; acc[3][2] += a.w * b.z; acc[3][3] += a.w * b.w;
    }
    __syncthreads();
  }
  unsigned short* hsu = (unsigned short*)Hs;
#pragma unroll
  for (int i = 0; i < 4; ++i) {
    int gr = row0 + tr * 4 + i;
    if (gr < N) {
      float dd = dis[gr];
      ushort4 v;
      v.x = __half_as_ushort(__float2half_rn(acc[i][0] * dd));
      v.y = __half_as_ushort(__float2half_rn(acc[i][1] * dd));
      v.z = __half_as_ushort(__float2half_rn(acc[i][2] * dd));
      v.w = __half_as_ushort(__float2half_rn(acc[i][3] * dd));
      *(ushort4*)&hsu[(size_t)gr * 64 + tc * 4] = v;
    }
  }
}

// Wave-per-row pull aggregation, half2 lanes, 2 edges per wave (one per
// 32-lane half), 8 edges per main iteration (4 line loads in flight/half):
//   Y[n] = act( dis[n] * ( sum_{s in row n} Hs[s] + Hs[n] ) + b )
__global__ __launch_bounds__(256) void agg_fused_kernel(const __half* __restrict__ Hs,
                                                        const int* __restrict__ esrc,
                                                        const int* __restrict__ rowptr,
                                                        const float* __restrict__ dis,
                                                        const float* __restrict__ b,
                                                        float* __restrict__ Y,
                                                        int N, int relu) {
  const int lane = threadIdx.x & 63;
  const int half = lane >> 5;       // which edge of the pair
  const int c = lane & 31;          // half2 column index (cols 2c, 2c+1)
  const int row = (blockIdx.x * 256 + threadIdx.x) >> 6;
  if (row >= N) return;
  const __half2* __restrict__ Hs2 = (const __half2*)Hs;
  const int k1 = rowptr[row + 1];
  int k = rowptr[row];
  float ax = 0.f, ay = 0.f;
  for (; k + 8 <= k1; k += 8) {
    int s0 = esrc[k + 0 + half];
    int s1 = esrc[k + 2 + half];
    int s2 = esrc[k + 4 + half];
    int s3 = esrc[k + 6 + half];
    float2 f0 = __half22float2(Hs2[(size_t)s0 * 32 + c]);
    float2 f1 = __half22float2(Hs2[(size_t)s1 * 32 + c]);
    float2 f2 = __half22float2(Hs2[(size_t)s2 * 32 + c]);
    float2 f3 = __half22float2(Hs2[(size_t)s3 * 32 + c]);
    ax += f0.x + f1.x + f2.x + f3.x;
    ay += f0.y + f1.y + f2.y + f3.y;
  }
  for (; k < k1; k += 2) {
    int kk = k + half;
    if (kk < k1) {
      float2 f = __half22float2(Hs2[(size_t)esrc[kk] * 32 + c]);
      ax += f.x; ay += f.y;
    }
  }
  ax += __shfl_xor(ax, 32);
  ay += __shfl_xor(ay, 32);
  if (half == 0) {
    float2 sf = __half22float2(Hs2[(size_t)row * 32 + c]);
    float dd = dis[row];
    float vx = dd * (ax + sf.x) + b[2 * c];
    float vy = dd * (ay + sf.y) + b[2 * c + 1];
    if (relu) { vx = fmaxf(vx, 0.f); vy = fmaxf(vy, 0.f); }
    *(float2*)&Y[(size_t)row * 64 + 2 * c] = make_float2(vx, vy);
  }
}

// Final layer: cols 0..31 -> mu (+bmu), cols 32..63 -> logvar (+blv).
__global__ __launch_bounds__(256) void agg_mulv_kernel(const __half* __restrict__ Hs,
                                                       const int* __restrict__ esrc,
                                                       const int* __restrict__ rowptr,
                                                       const float* __restrict__ dis,
                                                       const float* __restrict__ bmu,
                                                       const float* __restrict__ blv,
                                                       float* __restrict__ out, int N) {
  const int lane = threadIdx.x & 63;
  const int half = lane >> 5;
  const int c = lane & 31;
  const int row = (blockIdx.x * 256 + threadIdx.x) >> 6;
  if (row >= N) return;
  const __half2* __restrict__ Hs2 = (const __half2*)Hs;
  const int k1 = rowptr[row + 1];
  int k = rowptr[row];
  float ax = 0.f, ay = 0.f;
  for (; k + 8 <= k1; k += 8) {
    int s0 = esrc[k + 0 + half];
    int s1 = esrc[k + 2 + half];
    int s2 = esrc[k + 4 + half];
    int s3 = esrc[k + 6 + half];
    float2 f0 = __half22float2(Hs2[(size_t)s0 * 32 + c]);
    float2 f1 = __half22float2(Hs2[(size_t)s1 * 32 + c]);
    float2 f2 = __half22float2(Hs2[(size_t)s2 * 32 + c]);
    float2 f3 = __half22float2(Hs2[(size_t)s3 * 32 + c]);
    ax += f0.x + f1.x + f2.x + f3.x;
    ay += f0.y + f1.y + f2.y + f3.y;
  }
  for (; k < k1; k += 2) {
    int kk = k + half;
    if (kk < k1) {
      float2 f = __half22float2(Hs2[(size_t)esrc[kk] * 32 + c]);
      ax += f.x; ay += f.y;
    }
  }
  ax += __shfl_xor(ax, 32);
  ay += __shfl_xor(ay, 32);
  if (half == 0) {
    float2 sf = __half22float2(Hs2[(size_t)row * 32 + c]);
    float dd = dis[row];
    float vx = dd * (ax + sf.x);
    float vy = dd * (ay + sf.y);
    if (c < 16) {  // cols 2c,2c+1 in [0,32) -> mu
      vx += bmu[2 * c]; vy += bmu[2 * c + 1];
      *(float2*)&out[(size_t)row * 32 + 2 * c] = make_float2(vx, vy);
    } else {       // cols in [32,64) -> logvar
      int cc = 2 * c - 32;
      vx += blv[cc]; vy += blv[cc + 1];
      *(float2*)&out[(size_t)N * 32 + (size_t)row * 32 + cc] = make_float2(vx, vy);
    }
  }
}

extern "C" void kernel_launch(void* const* d_in, const int* in_sizes, int n_in,
                              void* d_out, int out_size, void* d_ws, size_t ws_size,
                              hipStream_t stream) {
  const float* x   = (const float*)d_in[0];
  const int*   ei  = (const int*)d_in[1];
  const float* W1  = (const float*)d_in[2];
  const float* b1  = (const float*)d_in[3];
  const float* W2  = (const float*)d_in[4];
  const float* b2  = (const float*)d_in[5];
  const float* Wmu = (const float*)d_in[6];
  const float* bmu = (const float*)d_in[7];
  const float* Wlv = (const float*)d_in[8];
  const float* blv = (const float*)d_in[9];

  const int N = in_sizes[0] / 128;
  const int E = in_sizes[1] / 2;
  const int* src = ei;
  const int* dst = ei + E;

  const int K = (N + 127) >> 7;        // coarse buckets (782), K <= 1024
  const int M = K * B1;                // hist2 entries
  const int chunk = (E + B1 - 1) / B1; // edges per pass-1 block

  const size_t N64 = (size_t)N * 64;
  __half* Hs    = (__half*)d_ws;            // N*64 fp16
  float* YBUF   = (float*)(Hs + N64);       // N*64 fp32
  float* dis    = YBUF + N64;               // N
  int*   rowptr = (int*)(dis + N);          // N+1
  int*   hist2  = rowptr + N + 1;           // K*B1 (becomes off2 after scan)
  int*   bsum   = hist2 + M;                // K (<=1024)
  int*   ebuf   = bsum + 1024;              // E packed (local<<17|src)
  int*   esrc   = ebuf + E;                 // E (CSR column indices)
  float* Wc     = (float*)(esrc + E);       // 64*64
  float* out    = (float*)d_out;

  const int rowBlocks = (N * 64 + 255) / 256;
  const int gemmBlocks = (N + 63) / 64;

  // ---- CSR build: counting sort by dst (also yields rowptr and dis) ----
  histk_kernel<<<B1, 256, 0, stream>>>(dst, hist2, E, K, chunk);
  scanA_kernel<<<K, 256, 0, stream>>>(hist2, hist2, bsum, M);
  scanB_kernel<<<1, 1024, 0, stream>>>(bsum, K);
  scanC_kernel<<<K, 256, 0, stream>>>(hist2, bsum, M);
  scat1_kernel<<<B1, 256, 0, stream>>>(src, dst, hist2, ebuf, E, K, chunk);
  bsort_kernel<<<K, 256, 0, stream>>>(ebuf, hist2, esrc, rowptr, dis, N, E, K);
  packw_kernel<<<16, 256, 0, stream>>>(Wmu, Wlv, Wc);

  // ---- layer 1: 128 -> 64, relu ----
  gemm64_kernel<<<gemmBlocks, 256, 0, stream>>>(x, W1, dis, Hs, N, 128);
  agg_fused_kernel<<<rowBlocks, 256, 0, stream>>>(Hs, esrc, rowptr, dis, b1, YBUF, N, 1);

  // ---- layer 2: 64 -> 64, relu ----
  gemm64_kernel<<<gemmBlocks, 256, 0, stream>>>(YBUF, W2, dis, Hs, N, 64);
  agg_fused_kernel<<<rowBlocks, 256, 0, stream>>>(Hs, esrc, rowptr, dis, b2, YBUF, N, 1);

  // ---- layer 3: 64 -> [32 mu | 32 logvar] ----
  gemm64_kernel<<<gemmBlocks, 256, 0, stream>>>(YBUF, Wc, dis, Hs, N, 64);
  agg_mulv_kernel<<<rowBlocks, 256, 0, stream>>>(Hs, esrc, rowptr, dis, bmu, blv, out, N);
}

// Round 8
// 362.200 us; speedup vs baseline: 3.7474x; 1.1765x over previous
//
#include <hip/hip_runtime.h>
#include <hip/hip_fp16.h>

// ---------------------------------------------------------------------------
// GCN encoder (VGAE): 3x GCNConv, N=100000 nodes, E=1.6M edges.
// Round 8 == round 7 resubmit (container failed twice; kernel never ran).
// MFMA f16 GEMM. R6 counters: fp32 gemm64 = 63us x3, 1.2M LDS bank
// conflicts, VALUBusy 23%, occ 31% -> issue/conflict-bound, 6x off roofline.
// gemm_mfma: v_mfma_f32_16x16x32_f16, A-frag loaded straight from global
// in fragment layout (row=lane&15, k=(lane>>4)*8+i), W pre-transposed+padded
// fp16 in global (packwT) -> contiguous LDS copy, B-frag ds_read_b128 with
// 2-way-max bank aliasing (free). D-layout per m89: col=lane&15,
// row=(lane>>4)*4+reg. Epilogue: Hs = D * dis[row] stored fp16.
// agg writes Y fp16 (half2) so layer-2/3 GEMMs read half the bytes.
// CSR counting sort (histk/scan/scat1/bsort) unchanged from r5/r6.
// ---------------------------------------------------------------------------

#define B1 256  // pass-1 block count (histk / scat1)

typedef _Float16 f16x8 __attribute__((ext_vector_type(8)));
typedef float f32x4 __attribute__((ext_vector_type(4)));

// per-block coarse histogram: hist2[k*B1 + b] = #edges of block b in bucket k
__global__ __launch_bounds__(256) void histk_kernel(const int* __restrict__ dst,
                                                    int* __restrict__ hist2,
                                                    int E, int K, int chunk) {
  __shared__ int h[1024];
  for (int i = threadIdx.x; i < K; i += 256) h[i] = 0;
  __syncthreads();
  const int e0 = blockIdx.x * chunk;
  const int e1 = min(E, e0 + chunk);
  for (int e = e0 + threadIdx.x; e < e1; e += 256)
    atomicAdd(&h[dst[e] >> 7], 1);
  __syncthreads();
  for (int i = threadIdx.x; i < K; i += 256)
    hist2[i * B1 + blockIdx.x] = h[i];
}

// ---- 3-phase exclusive scan over M = K*B1 ints (in-place safe) ----
__global__ __launch_bounds__(256) void scanA_kernel(const int* __restrict__ cnt,
                                                    int* __restrict__ excl,
                                                    int* __restrict__ bsum, int M) {
  __shared__ int sm[256];
  const int tid = threadIdx.x;
  const int i = blockIdx.x * 256 + tid;
  int v = (i < M) ? cnt[i] : 0;
  sm[tid] = v;
  __syncthreads();
#pragma unroll
  for (int off = 1; off < 256; off <<= 1) {
    int t = (tid >= off) ? sm[tid - off] : 0;
    __syncthreads();
    sm[tid] += t;
    __syncthreads();
  }
  if (i < M) excl[i] = sm[tid] - v;
  if (tid == 255) bsum[blockIdx.x] = sm[255];
}

__global__ __launch_bounds__(1024) void scanB_kernel(int* __restrict__ bsum, int nb) {
  __shared__ int sm[1024];
  const int tid = threadIdx.x;
  int v = (tid < nb) ? bsum[tid] : 0;
  sm[tid] = v;
  __syncthreads();
#pragma unroll
  for (int off = 1; off < 1024; off <<= 1) {
    int t = (tid >= off) ? sm[tid - off] : 0;
    __syncthreads();
    sm[tid] += t;
    __syncthreads();
  }
  if (tid < nb) bsum[tid] = sm[tid] - v;
}

__global__ __launch_bounds__(256) void scanC_kernel(int* __restrict__ data,
                                                    const int* __restrict__ bsum, int M) {
  int i = blockIdx.x * 256 + threadIdx.x;
  if (i < M) data[i] += bsum[i >> 8];
}

// pass-1 scatter: block b writes its edges into its private segment of each
// bucket: ebuf[off2[k][b] + local++] = (dstLocal<<17) | src
__global__ __launch_bounds__(256) void scat1_kernel(const int* __restrict__ src,
                                                    const int* __restrict__ dst,
                                                    const int* __restrict__ off2,
                                                    int* __restrict__ ebuf,
                                                    int E, int K, int chunk) {
  __shared__ int base[1024];
  __shared__ int cur[1024];
  for (int i = threadIdx.x; i < K; i += 256) {
    base[i] = off2[i * B1 + blockIdx.x];
    cur[i] = 0;
  }
  __syncthreads();
  const int e0 = blockIdx.x * chunk;
  const int e1 = min(E, e0 + chunk);
  for (int e = e0 + threadIdx.x; e < e1; e += 256) {
    int d = dst[e];
    int k = d >> 7;
    int p = base[k] + atomicAdd(&cur[k], 1);
    ebuf[p] = ((d & 127) << 17) | src[e];  // src < 2^17 (N=100000)
  }
}

// pass-2: one block per bucket (128 rows). Exact per-row CSR in LDS; dense
// esrc writes; emits rowptr and dis.
__global__ __launch_bounds__(256) void bsort_kernel(const int* __restrict__ ebuf,
                                                    const int* __restrict__ off2,
                                                    int* __restrict__ esrc,
                                                    int* __restrict__ rowptr,
                                                    float* __restrict__ dis,
                                                    int N, int E, int K) {
  const int k = blockIdx.x;
  const int tid = threadIdx.x;
  const int s0 = off2[k * B1];
  const int s1 = (k + 1 < K) ? off2[(k + 1) * B1] : E;
  const int cnt = s1 - s0;
  __shared__ int sm[128];
  __shared__ int rexcl[128];
  __shared__ int rcur[128];
  if (tid < 128) sm[tid] = 0;
  __syncthreads();
  for (int i = tid; i < cnt; i += 256)
    atomicAdd(&sm[ebuf[s0 + i] >> 17], 1);
  __syncthreads();
  int myc = (tid < 128) ? sm[tid] : 0;
#pragma unroll
  for (int off = 1; off < 128; off <<= 1) {  // Hillis-Steele inclusive
    int t = (tid >= off && tid < 128) ? sm[tid - off] : 0;
    __syncthreads();
    if (tid < 128) sm[tid] += t;
    __syncthreads();
  }
  if (tid < 128) {
    int ex = sm[tid] - myc;
    rexcl[tid] = ex;
    rcur[tid] = 0;
    int row = (k << 7) + tid;
    if (row < N) {
      rowptr[row] = s0 + ex;
      dis[row] = rsqrtf((float)myc + 1.0f);
    }
  }
  if (k == K - 1 && tid == 0) rowptr[N] = E;
  __syncthreads();
  for (int i = tid; i < cnt; i += 256) {
    int v = ebuf[s0 + i];
    int r = v >> 17;
    int p = s0 + rexcl[r] + atomicAdd(&rcur[r], 1);
    esrc[p] = v & 0x1FFFF;
  }
}

// Pre-transpose weights to fp16, padded k-dim (+8) for LDS bank spread:
//  W1t[c*136+k] = W1[k*64+c] (k<128), W2t[c*72+k] = W2[k*64+c] (k<64),
//  Wct[c*72+k] = [Wmu|Wlv] packed (k<64). Pads = 0.
__global__ __launch_bounds__(256) void packwT_kernel(const float* __restrict__ W1,
                                                     const float* __restrict__ W2,
                                                     const float* __restrict__ Wmu,
                                                     const float* __restrict__ Wlv,
                                                     __half* __restrict__ W1t,
                                                     __half* __restrict__ W2t,
                                                     __half* __restrict__ Wct) {
  int i = blockIdx.x * 256 + threadIdx.x;
  if (i < 64 * 136) {
    int c = i / 136, k = i % 136;
    W1t[i] = (k < 128) ? __float2half_rn(W1[k * 64 + c]) : __float2half_rn(0.f);
  }
  if (i < 64 * 72) {
    int c = i / 72, k = i % 72;
    W2t[i] = (k < 64) ? __float2half_rn(W2[k * 64 + c]) : __float2half_rn(0.f);
    float wc = 0.f;
    if (k < 64) wc = (c < 32) ? Wmu[k * 32 + c] : Wlv[k * 32 + (c - 32)];
    Wct[i] = __float2half_rn(wc);
  }
}

// MFMA GEMM: Hs(N x 64) = (Xin(N x DIN) @ W(DIN x 64)) * dis[row], fp16 out.
// Block = 64 nodes (4 waves x 16), per wave 4 col-tiles of 16.
// A-frag direct from global (row=lane&15, k=(lane>>4)*8+i); B from LDS Wt.
template <int DIN, bool F32IN>
__global__ __launch_bounds__(256) void gemm_mfma_kernel(const void* __restrict__ Xin,
                                                        const __half* __restrict__ Wt,
                                                        const float* __restrict__ dis,
                                                        __half* __restrict__ Hs, int N) {
  constexpr int KP = DIN + 8;  // padded k stride (halfs); 272B/144B rows
  __shared__ __half sW[64 * KP];
  const int tid = threadIdx.x;
  for (int i = tid * 8; i < 64 * KP; i += 256 * 8)
    *(f16x8*)&sW[i] = *(const f16x8*)&Wt[i];
  __syncthreads();

  const int w = tid >> 6;
  const int lane = tid & 63;
  const int r16 = lane & 15;   // A row within 16 / D col within 16
  const int kq = lane >> 4;    // k-quad: k = kq*8 + i ; D row = kq*4 + j
  const int nodeA = blockIdx.x * 64 + w * 16 + r16;
  const int nodeAc = min(nodeA, N - 1);

  f32x4 acc[4];
#pragma unroll
  for (int ct = 0; ct < 4; ++ct) acc[ct] = (f32x4){0.f, 0.f, 0.f, 0.f};

#pragma unroll
  for (int kt = 0; kt < DIN / 32; ++kt) {
    const int kb = kt * 32 + kq * 8;
    f16x8 a;
    if constexpr (F32IN) {
      const float* X = (const float*)Xin;
      float4 a0 = *(const float4*)&X[(size_t)nodeAc * DIN + kb];
      float4 a1 = *(const float4*)&X[(size_t)nodeAc * DIN + kb + 4];
      a[0] = (_Float16)a0.x; a[1] = (_Float16)a0.y;
      a[2] = (_Float16)a0.z; a[3] = (_Float16)a0.w;
      a[4] = (_Float16)a1.x; a[5] = (_Float16)a1.y;
      a[6] = (_Float16)a1.z; a[7] = (_Float16)a1.w;
    } else {
      const __half* X = (const __half*)Xin;
      a = *(const f16x8*)&X[(size_t)nodeAc * DIN + kb];
    }
#pragma unroll
    for (int ct = 0; ct < 4; ++ct) {
      f16x8 bf = *(const f16x8*)&sW[(ct * 16 + r16) * KP + kb];
      acc[ct] = __builtin_amdgcn_mfma_f32_16x16x32_f16(a, bf, acc[ct], 0, 0, 0);
    }
  }

  // D: row = kq*4 + j, col = ct*16 + r16 (m89 layout, dtype-independent)
#pragma unroll
  for (int j = 0; j < 4; ++j) {
    const int orow = blockIdx.x * 64 + w * 16 + kq * 4 + j;
    if (orow < N) {
      const float dd = dis[orow];
#pragma unroll
      for (int ct = 0; ct < 4; ++ct)
        Hs[(size_t)orow * 64 + ct * 16 + r16] = __float2half_rn(acc[ct][j] * dd);
    }
  }
}

// Wave-per-row pull aggregation, half2 lanes, 2 edges per wave (one per
// 32-lane half), 8 edges per main iteration; fp16 Y output:
//   Y[n] = act( dis[n] * ( sum_{s in row n} Hs[s] + Hs[n] ) + b )
__global__ __launch_bounds__(256) void agg_fused_kernel(const __half* __restrict__ Hs,
                                                        const int* __restrict__ esrc,
                                                        const int* __restrict__ rowptr,
                                                        const float* __restrict__ dis,
                                                        const float* __restrict__ b,
                                                        __half* __restrict__ Y,
                                                        int N, int relu) {
  const int lane = threadIdx.x & 63;
  const int half = lane >> 5;       // which edge of the pair
  const int c = lane & 31;          // half2 column index (cols 2c, 2c+1)
  const int row = (blockIdx.x * 256 + threadIdx.x) >> 6;
  if (row >= N) return;
  const __half2* __restrict__ Hs2 = (const __half2*)Hs;
  const int k1 = rowptr[row + 1];
  int k = rowptr[row];
  float ax = 0.f, ay = 0.f;
  for (; k + 8 <= k1; k += 8) {
    int s0 = esrc[k + 0 + half];
    int s1 = esrc[k + 2 + half];
    int s2 = esrc[k + 4 + half];
    int s3 = esrc[k + 6 + half];
    float2 f0 = __half22float2(Hs2[(size_t)s0 * 32 + c]);
    float2 f1 = __half22float2(Hs2[(size_t)s1 * 32 + c]);
    float2 f2 = __half22float2(Hs2[(size_t)s2 * 32 + c]);
    float2 f3 = __half22float2(Hs2[(size_t)s3 * 32 + c]);
    ax += f0.x + f1.x + f2.x + f3.x;
    ay += f0.y + f1.y + f2.y + f3.y;
  }
  for (; k < k1; k += 2) {
    int kk = k + half;
    if (kk < k1) {
      float2 f = __half22float2(Hs2[(size_t)esrc[kk] * 32 + c]);
      ax += f.x; ay += f.y;
    }
  }
  ax += __shfl_xor(ax, 32);
  ay += __shfl_xor(ay, 32);
  if (half == 0) {
    float2 sf = __half22float2(Hs2[(size_t)row * 32 + c]);
    float dd = dis[row];
    float vx = dd * (ax + sf.x) + b[2 * c];
    float vy = dd * (ay + sf.y) + b[2 * c + 1];
    if (relu) { vx = fmaxf(vx, 0.f); vy = fmaxf(vy, 0.f); }
    ((__half2*)Y)[(size_t)row * 32 + c] = __floats2half2_rn(vx, vy);
  }
}

// Final layer: cols 0..31 -> mu (+bmu), cols 32..63 -> logvar (+blv), fp32 out.
__global__ __launch_bounds__(256) void agg_mulv_kernel(const __half* __restrict__ Hs,
                                                       const int* __restrict__ esrc,
                                                       const int* __restrict__ rowptr,
                                                       const float* __restrict__ dis,
                                                       const float* __restrict__ bmu,
                                                       const float* __restrict__ blv,
                                                       float* __restrict__ out, int N) {
  const int lane = threadIdx.x & 63;
  const int half = lane >> 5;
  const int c = lane & 31;
  const int row = (blockIdx.x * 256 + threadIdx.x) >> 6;
  if (row >= N) return;
  const __half2* __restrict__ Hs2 = (const __half2*)Hs;
  const int k1 = rowptr[row + 1];
  int k = rowptr[row];
  float ax = 0.f, ay = 0.f;
  for (; k + 8 <= k1; k += 8) {
    int s0 = esrc[k + 0 + half];
    int s1 = esrc[k + 2 + half];
    int s2 = esrc[k + 4 + half];
    int s3 = esrc[k + 6 + half];
    float2 f0 = __half22float2(Hs2[(size_t)s0 * 32 + c]);
    float2 f1 = __half22float2(Hs2[(size_t)s1 * 32 + c]);
    float2 f2 = __half22float2(Hs2[(size_t)s2 * 32 + c]);
    float2 f3 = __half22float2(Hs2[(size_t)s3 * 32 + c]);
    ax += f0.x + f1.x + f2.x + f3.x;
    ay += f0.y + f1.y + f2.y + f3.y;
  }
  for (; k < k1; k += 2) {
    int kk = k + half;
    if (kk < k1) {
      float2 f = __half22float2(Hs2[(size_t)esrc[kk] * 32 + c]);
      ax += f.x; ay += f.y;
    }
  }
  ax += __shfl_xor(ax, 32);
  ay += __shfl_xor(ay, 32);
  if (half == 0) {
    float2 sf = __half22float2(Hs2[(size_t)row * 32 + c]);
    float dd = dis[row];
    float vx = dd * (ax + sf.x);
    float vy = dd * (ay + sf.y);
    if (c < 16) {  // cols 2c,2c+1 in [0,32) -> mu
      vx += bmu[2 * c]; vy += bmu[2 * c + 1];
      *(float2*)&out[(size_t)row * 32 + 2 * c] = make_float2(vx, vy);
    } else {       // cols in [32,64) -> logvar
      int cc = 2 * c - 32;
      vx += blv[cc]; vy += blv[cc + 1];
      *(float2*)&out[(size_t)N * 32 + (size_t)row * 32 + cc] = make_float2(vx, vy);
    }
  }
}

extern "C" void kernel_launch(void* const* d_in, const int* in_sizes, int n_in,
                              void* d_out, int out_size, void* d_ws, size_t ws_size,
                              hipStream_t stream) {
  const float* x   = (const float*)d_in[0];
  const int*   ei  = (const int*)d_in[1];
  const float* W1  = (const float*)d_in[2];
  const float* b1  = (const float*)d_in[3];
  const float* W2  = (const float*)d_in[4];
  const float* b2  = (const float*)d_in[5];
  const float* Wmu = (const float*)d_in[6];
  const float* bmu = (const float*)d_in[7];
  const float* Wlv = (const float*)d_in[8];
  const float* blv = (const float*)d_in[9];

  const int N = in_sizes[0] / 128;
  const int E = in_sizes[1] / 2;
  const int* src = ei;
  const int* dst = ei + E;

  const int K = (N + 127) >> 7;        // coarse buckets (782), K <= 1024
  const int M = K * B1;                // hist2 entries
  const int chunk = (E + B1 - 1) / B1; // edges per pass-1 block

  const size_t N64 = (size_t)N * 64;
  __half* Hs    = (__half*)d_ws;            // N*64 fp16
  __half* Yh    = Hs + N64;                 // N*64 fp16
  __half* W1t   = Yh + N64;                 // 64*136
  __half* W2t   = W1t + 64 * 136;           // 64*72
  __half* Wct   = W2t + 64 * 72;            // 64*72
  float* dis    = (float*)(Wct + 64 * 72);  // N
  int*   rowptr = (int*)(dis + N);          // N+1
  int*   hist2  = rowptr + N + 1;           // K*B1 (becomes off2 after scan)
  int*   bsum   = hist2 + M;                // K (<=1024)
  int*   ebuf   = bsum + 1024;              // E packed (local<<17|src)
  int*   esrc   = ebuf + E;                 // E (CSR column indices)
  float* out    = (float*)d_out;

  const int rowBlocks = (N * 64 + 255) / 256;
  const int gemmBlocks = (N + 63) / 64;

  // ---- CSR build: counting sort by dst (also yields rowptr and dis) ----
  histk_kernel<<<B1, 256, 0, stream>>>(dst, hist2, E, K, chunk);
  scanA_kernel<<<K, 256, 0, stream>>>(hist2, hist2, bsum, M);
  scanB_kernel<<<1, 1024, 0, stream>>>(bsum, K);
  scanC_kernel<<<K, 256, 0, stream>>>(hist2, bsum, M);
  scat1_kernel<<<B1, 256, 0, stream>>>(src, dst, hist2, ebuf, E, K, chunk);
  bsort_kernel<<<K, 256, 0, stream>>>(ebuf, hist2, esrc, rowptr, dis, N, E, K);
  packwT_kernel<<<34, 256, 0, stream>>>(W1, W2, Wmu, Wlv, W1t, W2t, Wct);

  // ---- layer 1: 128 -> 64, relu ----
  gemm_mfma_kernel<128, true><<<gemmBlocks, 256, 0, stream>>>(x, W1t, dis, Hs, N);
  agg_fused_kernel<<<rowBlocks, 256, 0, stream>>>(Hs, esrc, rowptr, dis, b1, Yh, N, 1);

  // ---- layer 2: 64 -> 64, relu ----
  gemm_mfma_kernel<64, false><<<gemmBlocks, 256, 0, stream>>>(Yh, W2t, dis, Hs, N);
  agg_fused_kernel<<<rowBlocks, 256, 0, stream>>>(Hs, esrc, rowptr, dis, b2, Yh, N, 1);

  // ---- layer 3: 64 -> [32 mu | 32 logvar] ----
  gemm_mfma_kernel<64, false><<<gemmBlocks, 256, 0, stream>>>(Yh, Wct, dis, Hs, N);
  agg_mulv_kernel<<<rowBlocks, 256, 0, stream>>>(Hs, esrc, rowptr, dis, bmu, blv, out, N);
}